// Round 11
// baseline (317.648 us; speedup 1.0000x reference)
//
#include <hip/hip_runtime.h>

#define NTOK 4096
#define CHAN 512
#define GSIZE 65536
#define RSQRT2 0.7071067811865476f
#define QSCALE 0.2550316360552602f   // (1/sqrt(32)) * log2(e)  -> exp2 domain
#define WS_NEEDED ((size_t)(16384 + 8 * 1024 * 1024))

typedef unsigned short ushort_t;
typedef __attribute__((ext_vector_type(8))) short bf16x8;
typedef __attribute__((ext_vector_type(4))) float f32x4;

__device__ __forceinline__ ushort_t f2b(float f) {
    unsigned u = __float_as_uint(f);
    unsigned r = (u + 0x7FFFu + ((u >> 16) & 1u)) >> 16;
    return (ushort_t)r;
}
__device__ __forceinline__ unsigned pack2r(float a, float b) {
    unsigned ua = __float_as_uint(a), ub = __float_as_uint(b);
    return ((ua + 0x8000u) >> 16) | ((ub + 0x8000u) & 0xFFFF0000u);
}
__device__ __forceinline__ bf16x8 ldfrag(const ushort_t* p) {
    return __builtin_bit_cast(bf16x8, *(const uint4*)p);
}

__global__ void diag_kernel(float* out, float v) {
    if (threadIdx.x == 0 && blockIdx.x == 0) out[0] = v;
}

// ---- Fused GroupNorm: one pass over x computes per-channel sums, then both
// GN stats and both affine coefficient sets in closed form.
__global__ __launch_bounds__(256) void gn_all(const float* __restrict__ x,
                                              const float* __restrict__ gnw,
                                              const float* __restrict__ gnb,
                                              float* __restrict__ qa,
                                              float* __restrict__ qd,
                                              float* __restrict__ va,
                                              float* __restrict__ vd) {
    int g = blockIdx.x, t = threadIdx.x;
    int cl = t >> 4, sl = t & 15;          // channel-local 0..15, slice 0..15
    const float4* p = (const float4*)(x + (size_t)g * GSIZE + (size_t)cl * 4096);
    float s = 0.f, ss = 0.f;
    for (int i = 0; i < 64; i++) {
        float4 f = p[i * 16 + sl];
        s += f.x + f.y + f.z + f.w;
        ss += f.x * f.x + f.y * f.y + f.z * f.z + f.w * f.w;
    }
    #pragma unroll
    for (int off = 8; off > 0; off >>= 1) {
        s += __shfl_xor(s, off);
        ss += __shfl_xor(ss, off);
    }
    __shared__ float Sc[16], SSc[16];
    if (sl == 0) { Sc[cl] = s; SSc[cl] = ss; }
    __syncthreads();
    if (t < 16) {
        float S = Sc[t], SS = SSc[t];
        float gs = S, gss = SS;
        #pragma unroll
        for (int off = 8; off > 0; off >>= 1) {
            gs += __shfl_xor(gs, off);
            gss += __shfl_xor(gss, off);
        }
        float mu = gs * (1.f / GSIZE);
        float var = gss * (1.f / GSIZE) - mu * mu;
        float r1 = rsqrtf(var + 1e-6f);
        int c = g * 16 + t;
        float wc = gnw[c], bc = gnb[c];
        float a1 = r1 * wc;
        float d1 = bc - mu * a1;           // qn = a1*x + d1
        qa[c] = a1; qd[c] = d1;
        // stats of qn from channel sums
        float S2 = a1 * S + 4096.f * d1;
        float SS2 = a1 * a1 * SS + 2.f * a1 * d1 * S + 4096.f * d1 * d1;
        float gs2 = S2, gss2 = SS2;
        #pragma unroll
        for (int off = 8; off > 0; off >>= 1) {
            gs2 += __shfl_xor(gs2, off);
            gss2 += __shfl_xor(gss2, off);
        }
        float mu2 = gs2 * (1.f / GSIZE);
        float var2 = gss2 * (1.f / GSIZE) - mu2 * mu2;
        float r2 = rsqrtf(var2 + 1e-6f);
        float a2 = r2 * wc;
        va[c] = a1 * a2;                   // vn = a2*(qn-mu2)+bc
        vd[c] = a2 * (d1 - mu2) + bc;
    }
}

// ---- QKV projection. M=1536 (wq|wk|wv), tile 128m x 128n, K-step 32.
// buf0 -> Q^T [tok][512] prescaled by QSCALE; buf1 -> K^T [tok][512];
// buf2 -> V [chan][tok]. Weights converted fp32->bf16 during staging.
__global__ __launch_bounds__(256) void qkv_mfma(const float* __restrict__ x,
                                                const float* __restrict__ wq,
                                                const float* __restrict__ wk,
                                                const float* __restrict__ wv,
                                                const float* __restrict__ bq,
                                                const float* __restrict__ bk,
                                                const float* __restrict__ bv,
                                                const float* __restrict__ qa,
                                                const float* __restrict__ qd,
                                                const float* __restrict__ va,
                                                const float* __restrict__ vd,
                                                ushort_t* __restrict__ QT,
                                                ushort_t* __restrict__ KT,
                                                ushort_t* __restrict__ Vb) {
    __shared__ __align__(16) ushort_t Wl[128][40];
    __shared__ __align__(16) ushort_t Bn[128][40];
    __shared__ __align__(16) ushort_t Tl[128][72];
    int t = threadIdx.x;
    int nbase = blockIdx.x << 7;
    int y = blockIdx.y;                    // 0..11
    int buf = y >> 2;
    int obase = (y & 3) << 7;
    const float* W    = (buf == 0) ? wq : (buf == 1) ? wk : wv;
    const float* bias = (buf == 0) ? bq : (buf == 1) ? bk : bv;
    const float* affa = (buf == 0) ? qa : va;
    const float* affd = (buf == 0) ? qd : vd;

    int w = t >> 6, lane = t & 63, q15 = lane & 15, quad = lane >> 4;
    f32x4 acc[2][8];
    #pragma unroll
    for (int i = 0; i < 2; i++)
        #pragma unroll
        for (int j = 0; j < 8; j++) acc[i][j] = (f32x4){0.f, 0.f, 0.f, 0.f};

    int ml = t & 127, kg = t >> 7;         // staging roles
    for (int ck = 0; ck < 512; ck += 32) {
        __syncthreads();
        {   // A: 128 o-rows x 32 k, fp32 -> bf16
            const float* src = W + (size_t)(obase + ml) * 512 + ck + kg * 16;
            float4 f0 = *(const float4*)(src + 0);
            float4 f1 = *(const float4*)(src + 4);
            float4 f2 = *(const float4*)(src + 8);
            float4 f3 = *(const float4*)(src + 12);
            uint4 u0, u1;
            u0.x = pack2r(f0.x, f0.y); u0.y = pack2r(f0.z, f0.w);
            u0.z = pack2r(f1.x, f1.y); u0.w = pack2r(f1.z, f1.w);
            u1.x = pack2r(f2.x, f2.y); u1.y = pack2r(f2.z, f2.w);
            u1.z = pack2r(f3.x, f3.y); u1.w = pack2r(f3.z, f3.w);
            *(uint4*)&Wl[ml][kg * 16] = u0;
            *(uint4*)&Wl[ml][kg * 16 + 8] = u1;
        }
        {   // B: 128 n x 32 k from x with affine
            float v[16];
            #pragma unroll
            for (int i = 0; i < 16; i++) {
                int c = ck + kg * 16 + i;
                v[i] = affa[c] * x[(size_t)c * NTOK + nbase + ml] + affd[c];
            }
            uint4 u0, u1;
            u0.x = pack2r(v[0], v[1]);  u0.y = pack2r(v[2], v[3]);
            u0.z = pack2r(v[4], v[5]);  u0.w = pack2r(v[6], v[7]);
            u1.x = pack2r(v[8], v[9]);  u1.y = pack2r(v[10], v[11]);
            u1.z = pack2r(v[12], v[13]); u1.w = pack2r(v[14], v[15]);
            *(uint4*)&Bn[ml][kg * 16] = u0;
            *(uint4*)&Bn[ml][kg * 16 + 8] = u1;
        }
        __syncthreads();
        bf16x8 af0 = ldfrag(&Wl[w * 32 + q15][quad * 8]);
        bf16x8 af1 = ldfrag(&Wl[w * 32 + 16 + q15][quad * 8]);
        #pragma unroll
        for (int n8 = 0; n8 < 8; n8++) {
            bf16x8 bfv = ldfrag(&Bn[n8 * 16 + q15][quad * 8]);
            acc[0][n8] = __builtin_amdgcn_mfma_f32_16x16x32_bf16(af0, bfv, acc[0][n8], 0, 0, 0);
            acc[1][n8] = __builtin_amdgcn_mfma_f32_16x16x32_bf16(af1, bfv, acc[1][n8], 0, 0, 0);
        }
    }

    if (buf == 2) {   // V: [chan][tok] scalar stores
        #pragma unroll
        for (int mi = 0; mi < 2; mi++)
            #pragma unroll
            for (int r = 0; r < 4; r++) {
                int o = obase + w * 32 + mi * 16 + quad * 4 + r;
                float bo = bias[o];
                #pragma unroll
                for (int n8 = 0; n8 < 8; n8++)
                    Vb[(size_t)o * NTOK + nbase + n8 * 16 + q15] = f2b(acc[mi][n8][r] + bo);
            }
        return;
    }

    // Q^T / K^T: transpose through LDS, two 64-chan halves
    ushort_t* dstT = (buf == 0) ? QT : KT;
    float qs = (buf == 0) ? QSCALE : 1.0f;
    for (int half = 0; half < 2; half++) {
        __syncthreads();
        if ((w >> 1) == half) {
            int wl = w & 1;
            #pragma unroll
            for (int mi = 0; mi < 2; mi++)
                #pragma unroll
                for (int r = 0; r < 4; r++) {
                    int mt = w * 32 + mi * 16 + quad * 4 + r;
                    int mloc = wl * 32 + mi * 16 + quad * 4 + r;
                    float bo = bias[obase + mt];
                    #pragma unroll
                    for (int n8 = 0; n8 < 8; n8++)
                        Tl[n8 * 16 + q15][mloc] = f2b((acc[mi][n8][r] + bo) * qs);
                }
        }
        __syncthreads();
        #pragma unroll
        for (int b = 0; b < 4; b++) {
            int j = b * 256 + t;
            int row = j >> 3, ch = j & 7;
            uint4 u = *(const uint4*)&Tl[row][ch * 8];
            *(uint4*)&dstT[(size_t)(nbase + row) * 512 + obase + half * 64 + ch * 8] = u;
        }
    }
}

// ---- Attention v2: barrier-free. Q^T/K^T token-major -> direct global MFMA
// frags; V chan-major -> direct PV B-frags. Only P goes through (per-wave) LDS.
// Wave = 32 queries; block = 4 independent waves; softmax in exp2 domain
// (QSCALE folded into Q^T).
__global__ __launch_bounds__(256) void attn_v2(const ushort_t* __restrict__ QT,
                                               const ushort_t* __restrict__ KT,
                                               const ushort_t* __restrict__ V,
                                               ushort_t* __restrict__ OT) {
    __shared__ __align__(16) unsigned Plu[4][32][36];
    int h = blockIdx.y;
    int t = threadIdx.x;
    int w = t >> 6, lane = t & 63, q15 = lane & 15, quad = lane >> 4;
    int qbase = (blockIdx.x << 7) + w * 32;
    const ushort_t* Vh = V + (size_t)h * 32 * NTOK;
    int hc = h * 32;

    bf16x8 qf[2];
    #pragma unroll
    for (int qi = 0; qi < 2; qi++)
        qf[qi] = ldfrag(&QT[(size_t)(qbase + qi * 16 + q15) * 512 + hc + quad * 8]);

    f32x4 o[2][2];
    #pragma unroll
    for (int qi = 0; qi < 2; qi++)
        #pragma unroll
        for (int dc = 0; dc < 2; dc++) o[qi][dc] = (f32x4){0.f, 0.f, 0.f, 0.f};
    float l0 = 0.f, l1 = 0.f;

    for (int j0 = 0; j0 < NTOK; j0 += 64) {
        bf16x8 kf[4];
        #pragma unroll
        for (int kt = 0; kt < 4; kt++)
            kf[kt] = ldfrag(&KT[(size_t)(j0 + kt * 16 + q15) * 512 + hc + quad * 8]);

        f32x4 st[4][2];
        #pragma unroll
        for (int kt = 0; kt < 4; kt++)
            #pragma unroll
            for (int qi = 0; qi < 2; qi++) {
                f32x4 z = {0.f, 0.f, 0.f, 0.f};
                st[kt][qi] = __builtin_amdgcn_mfma_f32_16x16x32_bf16(kf[kt], qf[qi], z, 0, 0, 0);
            }

        #pragma unroll
        for (int kt = 0; kt < 4; kt++)
            #pragma unroll
            for (int r = 0; r < 4; r++) {
                float e0 = exp2f(st[kt][0][r]);
                float e1 = exp2f(st[kt][1][r]);
                st[kt][0][r] = e0; l0 += e0;
                st[kt][1][r] = e1; l1 += e1;
            }

        asm volatile("" ::: "memory");
        #pragma unroll
        for (int kt = 0; kt < 4; kt++)
            #pragma unroll
            for (int qi = 0; qi < 2; qi++) {
                uint2 pp;
                pp.x = pack2r(st[kt][qi][0], st[kt][qi][1]);
                pp.y = pack2r(st[kt][qi][2], st[kt][qi][3]);
                *(uint2*)&Plu[w][qi * 16 + q15][kt * 8 + quad * 2] = pp;
            }
        asm volatile("" ::: "memory");

        #pragma unroll
        for (int kc = 0; kc < 2; kc++) {
            bf16x8 vf0 = ldfrag(&Vh[(size_t)(q15) * NTOK + j0 + kc * 32 + quad * 8]);
            bf16x8 vf1 = ldfrag(&Vh[(size_t)(16 + q15) * NTOK + j0 + kc * 32 + quad * 8]);
            #pragma unroll
            for (int qi = 0; qi < 2; qi++) {
                uint4 pu = *(const uint4*)&Plu[w][qi * 16 + q15][kc * 16 + quad * 4];
                bf16x8 pf = __builtin_bit_cast(bf16x8, pu);
                o[qi][0] = __builtin_amdgcn_mfma_f32_16x16x32_bf16(pf, vf0, o[qi][0], 0, 0, 0);
                o[qi][1] = __builtin_amdgcn_mfma_f32_16x16x32_bf16(pf, vf1, o[qi][1], 0, 0, 0);
            }
        }
    }

    l0 += __shfl_xor(l0, 16); l0 += __shfl_xor(l0, 32);
    l1 += __shfl_xor(l1, 16); l1 += __shfl_xor(l1, 32);
    float li0 = 1.f / l0, li1 = 1.f / l1;

    #pragma unroll
    for (int r = 0; r < 4; r++) {
        int q = quad * 4 + r;
        float lr0 = __shfl(li0, q);        // li is quad-invariant; lane q has q15==q
        float lr1 = __shfl(li1, q);
        #pragma unroll
        for (int dc = 0; dc < 2; dc++) {
            OT[(size_t)(qbase + q) * 512 + hc + dc * 16 + q15]      = f2b(o[0][dc][r] * lr0);
            OT[(size_t)(qbase + 16 + q) * 512 + hc + dc * 16 + q15] = f2b(o[1][dc][r] * lr1);
        }
    }
}

// ---- Output projection: A = wo (fp32->bf16 staged), B = O^T direct global
// frags. Epilogue: (acc + bias + x) * RSQRT2, fp32.
__global__ __launch_bounds__(256) void oproj_mfma(const ushort_t* __restrict__ OT,
                                                  const float* __restrict__ wo,
                                                  const float* __restrict__ bo,
                                                  const float* __restrict__ x,
                                                  float* __restrict__ out) {
    __shared__ __align__(16) ushort_t Wl[64][40];
    int t = threadIdx.x;
    int nbase = blockIdx.x << 7;
    int obase = blockIdx.y << 6;
    int w = t >> 6, lane = t & 63, q15 = lane & 15, quad = lane >> 4;

    f32x4 acc[8];
    #pragma unroll
    for (int i = 0; i < 8; i++) acc[i] = (f32x4){0.f, 0.f, 0.f, 0.f};

    int ml = t & 63, kg = t >> 6;
    for (int ck = 0; ck < 512; ck += 32) {
        __syncthreads();
        {
            const float* src = wo + (size_t)(obase + ml) * 512 + ck + kg * 8;
            float4 f0 = *(const float4*)(src + 0);
            float4 f1 = *(const float4*)(src + 4);
            uint4 u;
            u.x = pack2r(f0.x, f0.y); u.y = pack2r(f0.z, f0.w);
            u.z = pack2r(f1.x, f1.y); u.w = pack2r(f1.z, f1.w);
            *(uint4*)&Wl[ml][kg * 8] = u;
        }
        __syncthreads();
        bf16x8 af = ldfrag(&Wl[w * 16 + q15][quad * 8]);
        #pragma unroll
        for (int n8 = 0; n8 < 8; n8++) {
            bf16x8 bfv = ldfrag(&OT[(size_t)(nbase + n8 * 16 + q15) * 512 + ck + quad * 8]);
            acc[n8] = __builtin_amdgcn_mfma_f32_16x16x32_bf16(af, bfv, acc[n8], 0, 0, 0);
        }
    }

    #pragma unroll
    for (int r = 0; r < 4; r++) {
        int o = obase + w * 16 + quad * 4 + r;
        float b = bo[o];
        #pragma unroll
        for (int n8 = 0; n8 < 8; n8++) {
            size_t idx = (size_t)o * NTOK + nbase + n8 * 16 + q15;
            out[idx] = (acc[n8][r] + b + x[idx]) * RSQRT2;
        }
    }
}

extern "C" void kernel_launch(void* const* d_in, const int* in_sizes, int n_in,
                              void* d_out, int out_size, void* d_ws, size_t ws_size,
                              hipStream_t stream) {
    const float* x   = (const float*)d_in[0];
    const float* gnw = (const float*)d_in[1];
    const float* gnb = (const float*)d_in[2];
    const float* wq  = (const float*)d_in[3];
    const float* bq  = (const float*)d_in[4];
    const float* wk  = (const float*)d_in[5];
    const float* bk  = (const float*)d_in[6];
    const float* wv  = (const float*)d_in[7];
    const float* bv  = (const float*)d_in[8];
    const float* wo  = (const float*)d_in[9];
    const float* bo  = (const float*)d_in[10];
    float* out = (float*)d_out;

    if (ws_size < WS_NEEDED) {
        diag_kernel<<<1, 64, 0, stream>>>(out, (float)(ws_size >> 16));
        return;
    }

    char* wsb = (char*)d_ws;
    float* qa = (float*)(wsb + 0);          // 2 KB each
    float* qd = (float*)(wsb + 2048);
    float* va = (float*)(wsb + 4096);
    float* vd = (float*)(wsb + 6144);
    ushort_t* QT = (ushort_t*)(wsb + 16384);               // 4 MB bf16 [4096][512]
    ushort_t* OT = (ushort_t*)(wsb + 16384 + 4194304);     // 4 MB bf16 [4096][512]
    ushort_t* KT = (ushort_t*)d_out;                        // 4 MB bf16 [4096][512]
    ushort_t* Vb = (ushort_t*)d_out + (size_t)CHAN * NTOK;  // 4 MB bf16 [512][4096]

    gn_all<<<32, 256, 0, stream>>>(x, gnw, gnb, qa, qd, va, vd);

    qkv_mfma<<<dim3(32, 12), 256, 0, stream>>>(x, wq, wk, wv, bq, bk, bv,
                                               qa, qd, va, vd, QT, KT, Vb);

    attn_v2<<<dim3(32, 16), 256, 0, stream>>>(QT, KT, Vb, OT);

    oproj_mfma<<<dim3(32, 8), 256, 0, stream>>>(OT, wo, bo, x, out);
}